// Round 1
// baseline (329.877 us; speedup 1.0000x reference)
//
#include <hip/hip_runtime.h>

#define PP 10
#define FF 64
#define LL 2
#define BLOCK 256

__device__ __forceinline__ float gelu_tanh(float x) {
    const float c = 0.7978845608028654f; // sqrt(2/pi)
    float x3 = x * x * x;
    float z = c * (x + 0.044715f * x3);
    // tanh(z) = 1 - 2/(1+exp(2z)); saturates correctly at +/-inf
    float e = __expf(2.0f * z);
    float th = 1.0f - 2.0f / (1.0f + e);
    return 0.5f * x * (1.0f + th);
}

__device__ __forceinline__ void layernorm10(const float* in, const float* g,
                                            const float* b, float* out) {
    float mu = 0.0f;
#pragma unroll
    for (int j = 0; j < PP; ++j) mu += in[j];
    mu *= 0.1f;
    float var = 0.0f;
#pragma unroll
    for (int j = 0; j < PP; ++j) { float d = in[j] - mu; var += d * d; }
    var *= 0.1f;
    float rs = rsqrtf(var + 1e-5f);
#pragma unroll
    for (int j = 0; j < PP; ++j) out[j] = (in[j] - mu) * rs * g[j] + b[j];
}

__global__ __launch_bounds__(BLOCK) void hqcnn_kernel(
    const float* __restrict__ x,       // B x 8
    const float* __restrict__ protos,  // PP x 8
    const float* __restrict__ Wv,      // LL x PP x PP
    const float* __restrict__ bv,      // LL x PP
    const float* __restrict__ Wo,      // LL x PP x PP
    const float* __restrict__ bo,      // LL x PP
    const float* __restrict__ ln1g, const float* __restrict__ ln1b,
    const float* __restrict__ ln2g, const float* __restrict__ ln2b,
    const float* __restrict__ W1,      // LL x PP x FF
    const float* __restrict__ b1,      // LL x FF
    const float* __restrict__ W2,      // LL x FF x PP
    const float* __restrict__ b2,      // LL x PP
    const float* __restrict__ Wc,      // PP
    const float* __restrict__ bc,      // 1
    float* __restrict__ out, int B)
{
    __shared__ float s_protos[PP * 8];
    __shared__ float s_Wv[LL * PP * PP], s_bv[LL * PP];
    __shared__ float s_Wo[LL * PP * PP], s_bo[LL * PP];
    __shared__ float s_ln1g[LL * PP], s_ln1b[LL * PP];
    __shared__ float s_ln2g[LL * PP], s_ln2b[LL * PP];
    __shared__ float s_W1[LL * PP * FF], s_b1[LL * FF];
    __shared__ float s_W2[LL * FF * PP], s_b2[LL * PP];
    __shared__ float s_Wc[PP];
    __shared__ float s_bc;

    const int t = threadIdx.x;
    for (int k = t; k < PP * 8; k += BLOCK) s_protos[k] = protos[k];
    for (int k = t; k < LL * PP * PP; k += BLOCK) { s_Wv[k] = Wv[k]; s_Wo[k] = Wo[k]; }
    for (int k = t; k < LL * PP; k += BLOCK) {
        s_bv[k] = bv[k]; s_bo[k] = bo[k];
        s_ln1g[k] = ln1g[k]; s_ln1b[k] = ln1b[k];
        s_ln2g[k] = ln2g[k]; s_ln2b[k] = ln2b[k];
        s_b2[k] = b2[k];
    }
    for (int k = t; k < LL * PP * FF; k += BLOCK) { s_W1[k] = W1[k]; s_W2[k] = W2[k]; }
    for (int k = t; k < LL * FF; k += BLOCK) s_b1[k] = b1[k];
    if (t < PP) s_Wc[t] = Wc[t];
    if (t == 0) s_bc = bc[0];
    __syncthreads();

    const int i = blockIdx.x * BLOCK + t;
    if (i >= B) return;

    // ---- kernel-distance features: seq[p] = exp(-||x - proto_p||^2) ----
    const float4 xa = ((const float4*)x)[i * 2];
    const float4 xb = ((const float4*)x)[i * 2 + 1];
    float xv[8] = {xa.x, xa.y, xa.z, xa.w, xb.x, xb.y, xb.z, xb.w};

    float seq[PP];
#pragma unroll
    for (int p = 0; p < PP; ++p) {
        float d = 0.0f;
#pragma unroll
        for (int k = 0; k < 8; ++k) {
            float df = xv[k] - s_protos[p * 8 + k];
            d += df * df;
        }
        seq[p] = __expf(-d);
    }

    // ---- 2 transformer layers (seq_len==1 -> attention output == v) ----
#pragma unroll
    for (int l = 0; l < LL; ++l) {
        float h[PP];
        layernorm10(seq, &s_ln1g[l * PP], &s_ln1b[l * PP], h);

        float v[PP];
#pragma unroll
        for (int o = 0; o < PP; ++o) {
            float a = s_bv[l * PP + o];
#pragma unroll
            for (int j = 0; j < PP; ++j) a += h[j] * s_Wv[l * PP * PP + j * PP + o];
            v[o] = a;
        }
#pragma unroll
        for (int o = 0; o < PP; ++o) {
            float a = s_bo[l * PP + o];
#pragma unroll
            for (int j = 0; j < PP; ++j) a += v[j] * s_Wo[l * PP * PP + j * PP + o];
            seq[o] += a;
        }

        float h2[PP];
        layernorm10(seq, &s_ln2g[l * PP], &s_ln2b[l * PP], h2);

        float acc[PP];
#pragma unroll
        for (int o = 0; o < PP; ++o) acc[o] = s_b2[l * PP + o];
#pragma unroll 8
        for (int f = 0; f < FF; ++f) {
            float tt = s_b1[l * FF + f];
#pragma unroll
            for (int j = 0; j < PP; ++j) tt += h2[j] * s_W1[l * PP * FF + j * FF + f];
            float u = gelu_tanh(tt);
#pragma unroll
            for (int o = 0; o < PP; ++o) acc[o] += u * s_W2[l * FF * PP + f * PP + o];
        }
#pragma unroll
        for (int o = 0; o < PP; ++o) seq[o] += acc[o];
    }

    // ---- classifier head + sigmoid ----
    float z = s_bc;
#pragma unroll
    for (int o = 0; o < PP; ++o) z += seq[o] * s_Wc[o];
    out[i] = 1.0f / (1.0f + __expf(-z));
}

extern "C" void kernel_launch(void* const* d_in, const int* in_sizes, int n_in,
                              void* d_out, int out_size, void* d_ws, size_t ws_size,
                              hipStream_t stream) {
    const float* x      = (const float*)d_in[0];
    const float* protos = (const float*)d_in[1];
    // d_in[2..5] = Wq,bq,Wk,bk — dead (seq_len==1 => softmax==1 => o==v)
    const float* Wv   = (const float*)d_in[6];
    const float* bv   = (const float*)d_in[7];
    const float* Wo   = (const float*)d_in[8];
    const float* bo   = (const float*)d_in[9];
    const float* ln1g = (const float*)d_in[10];
    const float* ln1b = (const float*)d_in[11];
    const float* ln2g = (const float*)d_in[12];
    const float* ln2b = (const float*)d_in[13];
    const float* W1   = (const float*)d_in[14];
    const float* b1   = (const float*)d_in[15];
    const float* W2   = (const float*)d_in[16];
    const float* b2   = (const float*)d_in[17];
    const float* Wc   = (const float*)d_in[18];
    const float* bc   = (const float*)d_in[19];
    float* out = (float*)d_out;

    const int B = in_sizes[0] / 8;
    const int grid = (B + BLOCK - 1) / BLOCK;
    hqcnn_kernel<<<grid, BLOCK, 0, stream>>>(x, protos, Wv, bv, Wo, bo,
                                             ln1g, ln1b, ln2g, ln2b,
                                             W1, b1, W2, b2, Wc, bc, out, B);
}

// Round 2
// 235.762 us; speedup vs baseline: 1.3992x; 1.3992x over previous
//
#include <hip/hip_runtime.h>

#define PP 10
#define FF 64
#define LL 2
#define BLOCK 256

// ---- workspace layout (float offsets, all 16B-aligned) ----
#define WS_P2   0      // p2[10]                (pad to 16)
#define WS_M1   16     // M1[L][10][10] fused diag(ln1g)@Wv@Wo
#define WS_C1   216    // c1[L][10] fused attn bias
#define WS_W1T  240    // W1t[L][64][10] = ln2g[j]*W1[j][f], transposed
#define WS_B1F  1520   // b1f[L][64] = b1 + ln2b @ W1
#define WS_TOTAL 1648

__device__ __forceinline__ float fast_sigmoid(float z) {
    return __builtin_amdgcn_rcpf(1.0f + __expf(-z));
}

// gelu(x) = 0.5x(1+tanh(c(x+0.044715x^3))) = x * sigmoid(2c(x+0.044715x^3))
__device__ __forceinline__ float gelu_fast(float x) {
    float x3 = x * x * x;
    float z2 = 1.5957691216057308f * x + 0.0713548162726f * x3;
    return x * __builtin_amdgcn_rcpf(1.0f + __expf(-z2));
}

__global__ __launch_bounds__(256) void prep_kernel(
    const float* __restrict__ protos,
    const float* __restrict__ Wv, const float* __restrict__ bv,
    const float* __restrict__ Wo, const float* __restrict__ bo,
    const float* __restrict__ ln1g, const float* __restrict__ ln1b,
    const float* __restrict__ ln2g, const float* __restrict__ ln2b,
    const float* __restrict__ W1, const float* __restrict__ b1,
    float* __restrict__ ws)
{
    const int t = threadIdx.x;
    // p2
    if (t < PP) {
        float s = 0.0f;
        for (int k = 0; k < 8; ++k) { float v = protos[t * 8 + k]; s += v * v; }
        ws[WS_P2 + t] = s;
    }
    // M1[l][j][o] = ln1g[l][j] * sum_m Wv[l][j][m] * Wo[l][m][o]
    for (int idx = t; idx < LL * PP * PP; idx += 256) {
        int l = idx / (PP * PP);
        int r = idx % (PP * PP);
        int j = r / PP, o = r % PP;
        float s = 0.0f;
        for (int m = 0; m < PP; ++m)
            s += Wv[l * PP * PP + j * PP + m] * Wo[l * PP * PP + m * PP + o];
        ws[WS_M1 + idx] = ln1g[l * PP + j] * s;
    }
    // c1[l][o] = bo[l][o] + sum_m bv[l][m]*Wo[l][m][o]
    //          + sum_j ln1b[l][j] * (Wv@Wo)[l][j][o]
    for (int idx = t; idx < LL * PP; idx += 256) {
        int l = idx / PP, o = idx % PP;
        float s = bo[l * PP + o];
        for (int m = 0; m < PP; ++m) s += bv[l * PP + m] * Wo[l * PP * PP + m * PP + o];
        for (int j = 0; j < PP; ++j) {
            float wv_wo = 0.0f;
            for (int m = 0; m < PP; ++m)
                wv_wo += Wv[l * PP * PP + j * PP + m] * Wo[l * PP * PP + m * PP + o];
            s += ln1b[l * PP + j] * wv_wo;
        }
        ws[WS_C1 + idx] = s;
    }
    // W1t[l][f][j] = ln2g[l][j] * W1[l][j][f]
    for (int idx = t; idx < LL * FF * PP; idx += 256) {
        int l = idx / (FF * PP);
        int r = idx % (FF * PP);
        int f = r / PP, j = r % PP;
        ws[WS_W1T + idx] = ln2g[l * PP + j] * W1[l * PP * FF + j * FF + f];
    }
    // b1f[l][f] = b1[l][f] + sum_j ln2b[l][j]*W1[l][j][f]
    for (int idx = t; idx < LL * FF; idx += 256) {
        int l = idx / FF, f = idx % FF;
        float s = b1[l * FF + f];
        for (int j = 0; j < PP; ++j) s += ln2b[l * PP + j] * W1[l * PP * FF + j * FF + f];
        ws[WS_B1F + idx] = s;
    }
}

__global__ __launch_bounds__(BLOCK) void hqcnn_kernel(
    const float* __restrict__ x,       // B x 8
    const float* __restrict__ protos,  // PP x 8
    const float* __restrict__ W2,      // LL x FF x PP
    const float* __restrict__ b2,      // LL x PP
    const float* __restrict__ Wc,      // PP
    const float* __restrict__ bc,      // 1
    const float* __restrict__ ws,      // fused weights (uniform -> s_load)
    float* __restrict__ out, int B)
{
    const int t = threadIdx.x;
    const int i0 = blockIdx.x * (BLOCK * 2) + t;
    if (i0 >= B) return;
    const int i1raw = i0 + BLOCK;
    const int i1 = (i1raw < B) ? i1raw : i0;   // clamp; store guarded below

    // ---- load x (coalesced float4) ----
    float xv[2][8];
    {
        const float4 a0 = ((const float4*)x)[i0 * 2];
        const float4 a1 = ((const float4*)x)[i0 * 2 + 1];
        const float4 b0 = ((const float4*)x)[i1 * 2];
        const float4 b1_ = ((const float4*)x)[i1 * 2 + 1];
        xv[0][0]=a0.x; xv[0][1]=a0.y; xv[0][2]=a0.z; xv[0][3]=a0.w;
        xv[0][4]=a1.x; xv[0][5]=a1.y; xv[0][6]=a1.z; xv[0][7]=a1.w;
        xv[1][0]=b0.x; xv[1][1]=b0.y; xv[1][2]=b0.z; xv[1][3]=b0.w;
        xv[1][4]=b1_.x; xv[1][5]=b1_.y; xv[1][6]=b1_.z; xv[1][7]=b1_.w;
    }

    // ---- kernel features: seq[p] = exp(-(x2 + p2 - 2 x.proto))  (ref formula) ----
    float x2[2];
#pragma unroll
    for (int e = 0; e < 2; ++e) {
        float s = 0.0f;
#pragma unroll
        for (int k = 0; k < 8; ++k) s += xv[e][k] * xv[e][k];
        x2[e] = s;
    }
    float seq[2][PP];
#pragma unroll
    for (int p = 0; p < PP; ++p) {
        float p2 = ws[WS_P2 + p];
#pragma unroll
        for (int e = 0; e < 2; ++e) {
            float dot = 0.0f;
#pragma unroll
            for (int k = 0; k < 8; ++k) dot += xv[e][k] * protos[p * 8 + k];
            float sq = x2[e] + p2 - 2.0f * dot;
            seq[e][p] = __expf(-sq);
        }
    }

    // ---- 2 transformer layers ----
#pragma unroll
    for (int l = 0; l < LL; ++l) {
        // LN1 (affine folded into M1/c1): y = (seq - mu) * rs
        float y[2][PP];
#pragma unroll
        for (int e = 0; e < 2; ++e) {
            float mu = 0.0f;
#pragma unroll
            for (int j = 0; j < PP; ++j) mu += seq[e][j];
            mu *= 0.1f;
            float var = 0.0f;
#pragma unroll
            for (int j = 0; j < PP; ++j) { float d = seq[e][j] - mu; var += d * d; }
            var *= 0.1f;
            float rs = __builtin_amdgcn_rsqf(var + 1e-5f);
            float mrs = -mu * rs;
#pragma unroll
            for (int j = 0; j < PP; ++j) y[e][j] = seq[e][j] * rs + mrs;
        }
        // fused attention: seq += y @ M1 + c1
#pragma unroll
        for (int o = 0; o < PP; ++o) {
            float c = ws[WS_C1 + l * PP + o];
            float a0 = c, a1 = c;
#pragma unroll
            for (int j = 0; j < PP; ++j) {
                float w = ws[WS_M1 + l * PP * PP + j * PP + o];
                a0 += y[0][j] * w;
                a1 += y[1][j] * w;
            }
            seq[0][o] += a0;
            seq[1][o] += a1;
        }
        // LN2 (affine folded into W1t/b1f)
#pragma unroll
        for (int e = 0; e < 2; ++e) {
            float mu = 0.0f;
#pragma unroll
            for (int j = 0; j < PP; ++j) mu += seq[e][j];
            mu *= 0.1f;
            float var = 0.0f;
#pragma unroll
            for (int j = 0; j < PP; ++j) { float d = seq[e][j] - mu; var += d * d; }
            var *= 0.1f;
            float rs = __builtin_amdgcn_rsqf(var + 1e-5f);
            float mrs = -mu * rs;
#pragma unroll
            for (int j = 0; j < PP; ++j) y[e][j] = seq[e][j] * rs + mrs;
        }
        // FFN: seq += gelu(y @ W1t^T + b1f) @ W2 + b2
        float acc[2][PP];
#pragma unroll
        for (int o = 0; o < PP; ++o) {
            float b = b2[l * PP + o];
            acc[0][o] = b; acc[1][o] = b;
        }
#pragma unroll 2
        for (int f = 0; f < FF; ++f) {
            float bb = ws[WS_B1F + l * FF + f];
            float t0 = bb, t1 = bb;
#pragma unroll
            for (int j = 0; j < PP; ++j) {
                float w = ws[WS_W1T + l * FF * PP + f * PP + j];
                t0 += y[0][j] * w;
                t1 += y[1][j] * w;
            }
            float u0 = gelu_fast(t0);
            float u1 = gelu_fast(t1);
#pragma unroll
            for (int o = 0; o < PP; ++o) {
                float w = W2[l * FF * PP + f * PP + o];
                acc[0][o] += u0 * w;
                acc[1][o] += u1 * w;
            }
        }
#pragma unroll
        for (int o = 0; o < PP; ++o) {
            seq[0][o] += acc[0][o];
            seq[1][o] += acc[1][o];
        }
    }

    // ---- head + sigmoid ----
    float bcs = bc[0];
    float z0 = bcs, z1 = bcs;
#pragma unroll
    for (int o = 0; o < PP; ++o) {
        float w = Wc[o];
        z0 += seq[0][o] * w;
        z1 += seq[1][o] * w;
    }
    out[i0] = fast_sigmoid(z0);
    if (i1raw < B) out[i1raw] = fast_sigmoid(z1);
}

extern "C" void kernel_launch(void* const* d_in, const int* in_sizes, int n_in,
                              void* d_out, int out_size, void* d_ws, size_t ws_size,
                              hipStream_t stream) {
    const float* x      = (const float*)d_in[0];
    const float* protos = (const float*)d_in[1];
    // d_in[2..5] = Wq,bq,Wk,bk — dead (seq_len==1 => softmax==1 => o==v)
    const float* Wv   = (const float*)d_in[6];
    const float* bv   = (const float*)d_in[7];
    const float* Wo   = (const float*)d_in[8];
    const float* bo   = (const float*)d_in[9];
    const float* ln1g = (const float*)d_in[10];
    const float* ln1b = (const float*)d_in[11];
    const float* ln2g = (const float*)d_in[12];
    const float* ln2b = (const float*)d_in[13];
    const float* W1   = (const float*)d_in[14];
    const float* b1   = (const float*)d_in[15];
    const float* W2   = (const float*)d_in[16];
    const float* b2   = (const float*)d_in[17];
    const float* Wc   = (const float*)d_in[18];
    const float* bc   = (const float*)d_in[19];
    float* out = (float*)d_out;
    float* ws  = (float*)d_ws;

    prep_kernel<<<1, 256, 0, stream>>>(protos, Wv, bv, Wo, bo,
                                       ln1g, ln1b, ln2g, ln2b, W1, b1, ws);

    const int B = in_sizes[0] / 8;
    const int grid = (B + BLOCK * 2 - 1) / (BLOCK * 2);
    hqcnn_kernel<<<grid, BLOCK, 0, stream>>>(x, protos, W2, b2, Wc, bc, ws, out, B);
}